// Round 9
// baseline (1035.890 us; speedup 1.0000x reference)
//
#include <hip/hip_runtime.h>
#include <math.h>

// Problem constants (setup_inputs): B=8, C=64, N=4096, O=64, K=20
#define Bn 8
#define Cc 64
#define Nn 4096
#define Oo 64
#define Kk 20
#define QCAP 16              // per-row candidate queue capacity per tile
#define NTOT (Bn*Nn*Kk)      // 655360 elements per BN channel

typedef __attribute__((ext_vector_type(8))) short short8;
typedef __attribute__((ext_vector_type(4))) float f32x4;

__device__ __forceinline__ unsigned bf16_rn(float v) {
  unsigned u = __float_as_uint(v);
  return (u + 0x7FFFu + ((u >> 16) & 1)) >> 16;     // RN-even
}

// ---------------------------------------------------------------- k_split
// x fp32 [b][c][n] -> 3-term bf16 split transposed to [b][n][c], plus
// sq[b][n] = sum_c x^2 (folded here; k_sq kernel eliminated).
//   h = RN(x); m = RN(x-h); l = RN(x-h-m)   (x-h, x-h-m exact in fp32)
__global__ __launch_bounds__(256) void k_split(const float* __restrict__ x,
                                               unsigned short* __restrict__ xhi,
                                               unsigned short* __restrict__ xmid,
                                               unsigned short* __restrict__ xlo,
                                               float* __restrict__ sqv) {
  __shared__ float xs[64][68];                  // [c][n], float4-friendly pad
  int tid = threadIdx.x;
  int b = blockIdx.x & 7;
  int n0 = (blockIdx.x >> 3) << 6;
  // load tile: float4 rows (16 lanes x 16B = one 64-float row per 16 lanes)
  for (int i = 0; i < 4; i++) {
    int c = i * 16 + (tid >> 4);
    int n = (tid & 15) * 4;
    float4 v = *(const float4*)&x[((size_t)b * Cc + c) * Nn + n0 + n];
    *(float4*)&xs[c][n] = v;
  }
  __syncthreads();
  // split + transpose store: thread = (n, 4 consecutive c) -> ushort4 stores
  for (int i = 0; i < 4; i++) {
    int n = i * 16 + (tid >> 4);
    int c = (tid & 15) * 4;
    ushort4 h4, m4, l4;
    unsigned short* hp = (unsigned short*)&h4;
    unsigned short* mp = (unsigned short*)&m4;
    unsigned short* lp = (unsigned short*)&l4;
#pragma unroll
    for (int j = 0; j < 4; j++) {
      float v = xs[c + j][n];
      unsigned hb = bf16_rn(v);
      float hf = __uint_as_float(hb << 16);
      float r1 = v - hf;                                     // exact
      unsigned mb = bf16_rn(r1);
      float mf = __uint_as_float(mb << 16);
      float r2 = r1 - mf;                                    // exact
      unsigned lb = bf16_rn(r2);
      hp[j] = (unsigned short)hb;
      mp[j] = (unsigned short)mb;
      lp[j] = (unsigned short)lb;
    }
    size_t o = ((size_t)(b << 12) + n0 + n) * 64 + c;
    *(ushort4*)&xhi[o] = h4;
    *(ushort4*)&xmid[o] = m4;
    *(ushort4*)&xlo[o] = l4;
  }
  // sq for this block's 64 rows (lane n; xs col reads are 2-way = free)
  if (tid < 64) {
    float s = 0.f;
#pragma unroll
    for (int c = 0; c < 64; c++) { float v = xs[c][tid]; s = fmaf(v, v, s); }
    sqv[b * Nn + n0 + tid] = s;
  }
}

// ---------------------------------------------------------------- k_y1z
// y1 = xt*W1^T, z = xt*(W2-W1)^T. xs stored n-major so the x reads are
// float4 + wave-broadcast (nb is wave-uniform); W reads stride 129 (odd) ->
// conflict-free scalar ds_read.
__global__ __launch_bounds__(256) void k_y1z(const float* __restrict__ x,
                                             const float* __restrict__ Wm,
                                             float* __restrict__ y1,
                                             float* __restrict__ z) {
  __shared__ float xs[64][68];                  // [c][n]
  __shared__ float Wl[64][129];
  int tid = threadIdx.x;
  int b = blockIdx.x & 7;
  int n0 = (blockIdx.x >> 3) << 6;
  for (int i = tid; i < 64 * 128; i += 256) Wl[i >> 7][i & 127] = Wm[i];
  for (int i = 0; i < 4; i++) {
    int c = i * 16 + (tid >> 4);
    int n = (tid & 15) * 4;
    float4 v = *(const float4*)&x[((size_t)b * Cc + c) * Nn + n0 + n];
    *(float4*)&xs[c][n] = v;
  }
  __syncthreads();
  int o = tid & 63, ng = tid >> 6;              // ng == wave id -> nb uniform
  for (int p = 0; p < 4; p++) {
    int nb = p * 16 + ng * 4;
    float a1[4] = {0.f, 0.f, 0.f, 0.f};
    float a2[4] = {0.f, 0.f, 0.f, 0.f};
#pragma unroll 8
    for (int c = 0; c < 64; c++) {
      float4 xv = *(const float4*)&xs[c][nb];   // wave-broadcast
      float w1v = Wl[o][c], w2v = Wl[o][64 + c];
      float xa[4] = {xv.x, xv.y, xv.z, xv.w};
#pragma unroll
      for (int j = 0; j < 4; j++) {
        a1[j] = fmaf(xa[j], w1v, a1[j]);
        a2[j] = fmaf(xa[j], w2v, a2[j]);
      }
    }
#pragma unroll
    for (int j = 0; j < 4; j++) {
      size_t off = ((size_t)b * Nn + n0 + nb + j) * 64 + o;
      y1[off] = a1[j];
      z[off] = a2[j] - a1[j];
    }
  }
}

// ---------------------------------------------------------------- k_knn (v9)
// Round-8 structure (8-row waves, 64-col tiles, 3-term split-bf16 MFMA Gram,
// wave-private queues + sorted register top-20) with:
//  - AGGREGATED pushes: per pend-bit, ballot -> q-group mask -> 1 leader
//    atomicAdd + shfl base + popc-ranked slots (round 8's 16-way same-address
//    DS-atomic serialization was the 2.8e7 conflict source).
//  - QCAP 16 / strides 20 -> LDS 32.0KB -> 5 blocks/CU (20 waves).
__global__ __launch_bounds__(256, 5) void k_knn(const unsigned short* __restrict__ xhi,
                                                const unsigned short* __restrict__ xmid,
                                                const unsigned short* __restrict__ xlo,
                                                const float* __restrict__ sqv,
                                                int* __restrict__ idxout) {
  __shared__ alignas(16) short Bs[3][64][72];    // [h/m/l][m][c], padded
  __shared__ float thrS[32];
  __shared__ float sqs[64];
  __shared__ alignas(16) float qk[32][20];       // 80B rows: lanes bank-distinct
  __shared__ alignas(8) unsigned short qm[32][20];
  __shared__ int qcnt[32];

  const int tid = threadIdx.x;
  const int lane = tid & 63;
  const int w = tid >> 6;
  const int b = blockIdx.x & 7;                  // XCD swizzle: batch per XCD
  const int n0 = (blockIdx.x >> 3) << 5;         // 128 row-blocks x 32 rows
  const int lm = lane & 15;                      // candidate col / A row slot
  const int q = lane >> 4;                       // quad: C row = q*4+r
  const int myrow = w * 8 + lane;                // valid for lane<8 (handler)
  const bool handler = (lane < 8);

  // handler state: SORTED ascending 20-list in registers (lanes 0-7)
  float hk[Kk];
  int hix[Kk];
  float hthr = INFINITY;
#pragma unroll
  for (int kk = 0; kk < Kk; kk++) { hk[kk] = INFINITY; hix[kk] = 0; }

  if (handler) { thrS[myrow] = INFINITY; qcnt[myrow] = 0; }  // wave-private init

  // A fragments: wave w owns query rows n0+w*8 .. +7; rows 8-15 duplicate.
  const size_t arow = ((size_t)(b << 12) + n0 + w * 8 + (lm & 7)) * 64;
  short8 ah0 = *(const short8*)&xhi[arow + q * 8];
  short8 ah1 = *(const short8*)&xhi[arow + 32 + q * 8];
  short8 am0 = *(const short8*)&xmid[arow + q * 8];
  short8 am1 = *(const short8*)&xmid[arow + 32 + q * 8];
  short8 al0 = *(const short8*)&xlo[arow + q * 8];
  short8 al1 = *(const short8*)&xlo[arow + 32 + q * 8];

  f32x4 acc[4];

  for (int m0 = 0; m0 < Nn; m0 += 64) {
    __syncthreads();                              // all waves done reading Bs
    // stage B tile: 3 layers x 64 rows x 8 chunks of short8, coalesced
#pragma unroll
    for (int i = 0; i < 6; i++) {
      int f = i * 256 + tid;                      // [0,1536)
      int layer = f >> 9;
      int r = (f >> 3) & 63;
      int qq = f & 7;
      const unsigned short* src = (layer == 0) ? xhi : (layer == 1) ? xmid : xlo;
      short8 v = *(const short8*)&src[((size_t)(b << 12) + m0 + r) * 64 + qq * 8];
      *(short8*)&Bs[layer][r][qq * 8] = v;
    }
    if (tid < 16) ((float4*)sqs)[tid] = ((const float4*)(sqv + b * Nn + m0))[tid];
    __syncthreads();                              // staging visible

#pragma unroll
    for (int g = 0; g < 4; g++) {
      const int mr = g * 16 + lm;
      short8 bh0 = *(const short8*)&Bs[0][mr][q * 8];
      short8 bh1 = *(const short8*)&Bs[0][mr][32 + q * 8];
      short8 bm0 = *(const short8*)&Bs[1][mr][q * 8];
      short8 bm1 = *(const short8*)&Bs[1][mr][32 + q * 8];
      short8 bl0 = *(const short8*)&Bs[2][mr][q * 8];
      short8 bl1 = *(const short8*)&Bs[2][mr][32 + q * 8];
      f32x4 a = (f32x4){0.f, 0.f, 0.f, 0.f};
      a = __builtin_amdgcn_mfma_f32_16x16x32_bf16(am0, bm0, a, 0, 0, 0);  // mm
      a = __builtin_amdgcn_mfma_f32_16x16x32_bf16(am1, bm1, a, 0, 0, 0);
      a = __builtin_amdgcn_mfma_f32_16x16x32_bf16(ah0, bl0, a, 0, 0, 0);  // hl
      a = __builtin_amdgcn_mfma_f32_16x16x32_bf16(ah1, bl1, a, 0, 0, 0);
      a = __builtin_amdgcn_mfma_f32_16x16x32_bf16(al0, bh0, a, 0, 0, 0);  // lh
      a = __builtin_amdgcn_mfma_f32_16x16x32_bf16(al1, bh1, a, 0, 0, 0);
      a = __builtin_amdgcn_mfma_f32_16x16x32_bf16(ah0, bm0, a, 0, 0, 0);  // hm
      a = __builtin_amdgcn_mfma_f32_16x16x32_bf16(ah1, bm1, a, 0, 0, 0);
      a = __builtin_amdgcn_mfma_f32_16x16x32_bf16(am0, bh0, a, 0, 0, 0);  // mh
      a = __builtin_amdgcn_mfma_f32_16x16x32_bf16(am1, bh1, a, 0, 0, 0);
      a = __builtin_amdgcn_mfma_f32_16x16x32_bf16(ah0, bh0, a, 0, 0, 0);  // hh
      a = __builtin_amdgcn_mfma_f32_16x16x32_bf16(ah1, bh1, a, 0, 0, 0);
      acc[g] = a;
    }

    // keys = sq[m] - 2*dot; only q<2 lanes hold unique query rows (0..7)
    unsigned pend = 0;
    if (q < 2) {
      float tl[4];
#pragma unroll
      for (int r = 0; r < 4; r++) tl[r] = thrS[w * 8 + q * 4 + r];
#pragma unroll
      for (int g = 0; g < 4; g++) {
        float sv = sqs[g * 16 + lm];
#pragma unroll
        for (int r = 0; r < 4; r++) {
          float key = fmaf(-2.f, acc[g][r], sv);
          acc[g][r] = key;
          if (key < tl[r]) pend |= 1u << (g * 4 + r);
        }
      }
    }

    // wave-private push / drain: NO __syncthreads (DS in-order per wave)
    for (;;) {
      // aggregated push: per bit, one atomicAdd per q-group
#pragma unroll
      for (int bit = 0; bit < 16; bit++) {
        unsigned long long bal = __ballot(((pend >> bit) & 1u) != 0u);
        if (bal) {                                // wave-uniform skip
          unsigned gm = (unsigned)(bal >> (q << 4)) & 0xFFFFu;
          if (gm) {
            const int g = bit >> 2, r = bit & 3;
            int row = w * 8 + (q << 2) + r;
            int lead = __ffs(gm) - 1;             // lm of group leader
            int base = 0;
            if (lm == lead) base = atomicAdd(&qcnt[row], __popc(gm));
            base = __shfl(base, (q << 4) | lead);
            if ((pend >> bit) & 1u) {
              int slot = base + __popc(gm & ((1u << lm) - 1u));
              if (slot < QCAP) {
                qk[row][slot] = acc[g][r];
                qm[row][slot] = (unsigned short)(m0 + g * 16 + lm);
                pend &= ~(1u << bit);
              }
              // else: bit stays set -> retry after drain
            }
          }
        }
      }
      unsigned long long anyovf = __ballot(pend != 0);

      if (handler) {                             // 8 lanes drain 8 rows
        int cn = qcnt[myrow];
        if (cn > QCAP) cn = QCAP;
        for (int p0 = 0; p0 < cn; p0 += 4) {
          float4 kv4 = *(const float4*)&qk[myrow][p0];
          ushort4 mv4 = *(const ushort4*)&qm[myrow][p0];
          float kva[4] = {kv4.x, kv4.y, kv4.z, kv4.w};
          unsigned short mva[4] = {mv4.x, mv4.y, mv4.z, mv4.w};
#pragma unroll
          for (int j = 0; j < 4; j++) {
            if (p0 + j < cn && kva[j] < hthr) {
              float kv = kva[j];
              int mvi = (int)mva[j];
              bool cm[Kk];
#pragma unroll
              for (int kk = 0; kk < Kk; kk++) cm[kk] = kv < hk[kk];
#pragma unroll
              for (int kk = Kk - 1; kk >= 1; kk--) {
                hk[kk]  = cm[kk] ? (cm[kk - 1] ? hk[kk - 1]  : kv ) : hk[kk];
                hix[kk] = cm[kk] ? (cm[kk - 1] ? hix[kk - 1] : mvi) : hix[kk];
              }
              if (cm[0]) { hk[0] = kv; hix[0] = mvi; }
              hthr = hk[Kk - 1];
            }
          }
        }
        if (cn) { qcnt[myrow] = 0; thrS[myrow] = hthr; }
      }
      if (!anyovf) break;
      // refilter surviving bits against the tightened thresholds
      if (pend) {
        float tl[4];
#pragma unroll
        for (int r = 0; r < 4; r++) tl[r] = thrS[w * 8 + q * 4 + r];
#pragma unroll
        for (int g = 0; g < 4; g++)
#pragma unroll
          for (int r = 0; r < 4; r++) {
            unsigned bit = 1u << (g * 4 + r);
            if ((pend & bit) && acc[g][r] >= tl[r]) pend &= ~bit;
          }
      }
    }
  }

  // final write: handler lane owns row myrow's sorted list
  if (handler) {
    size_t base = ((size_t)b * Nn + n0 + myrow) * Kk;
#pragma unroll
    for (int kk = 0; kk < Kk; kk++) idxout[base + kk] = hix[kk];
  }
}

// ---------------------------------------------------------------- k_stats
// Per-block partial sums (no global atomic contention); k_reduce finishes.
__global__ __launch_bounds__(256) void k_stats(const float* __restrict__ y1,
                                               const float* __restrict__ z,
                                               const int* __restrict__ idxp,
                                               float* __restrict__ parts) {
  __shared__ float rs[4][64];
  __shared__ float rq[4][64];
  int tid = threadIdx.x;
  int o = tid & 63, g = tid >> 6;
  int b = blockIdx.x & 7;                       // XCD swizzle
  int n0 = (blockIdx.x >> 3) << 6;
  const float* y1b = y1 + (size_t)b * Nn * 64;
  float s = 0.f, ss = 0.f;
  for (int t = 0; t < 16; t++) {
    int n = n0 + g + t * 4;
    size_t base = (size_t)b * Nn + n;
    float zv = z[base * 64 + o];
    const int* ip = idxp + base * Kk;
#pragma unroll
    for (int k = 0; k < Kk; k++) {
      int j = ip[k];
      float hv = y1b[(size_t)j * 64 + o] + zv;
      s += hv;
      ss = fmaf(hv, hv, ss);
    }
  }
  rs[g][o] = s;
  rq[g][o] = ss;
  __syncthreads();
  if (tid < 64) {
    parts[(size_t)blockIdx.x * 128 + tid] = rs[0][tid] + rs[1][tid] + rs[2][tid] + rs[3][tid];
    parts[(size_t)blockIdx.x * 128 + 64 + tid] = rq[0][tid] + rq[1][tid] + rq[2][tid] + rq[3][tid];
  }
}

// ---------------------------------------------------------------- k_reduce
__global__ __launch_bounds__(128) void k_reduce(const float* __restrict__ parts,
                                                float* __restrict__ stats) {
  int tid = threadIdx.x;                         // [0,128)
  float s = 0.f;
  for (int i = 0; i < 512; i += 4) {
    s += parts[(size_t)i * 128 + tid] + parts[(size_t)(i + 1) * 128 + tid] +
         parts[(size_t)(i + 2) * 128 + tid] + parts[(size_t)(i + 3) * 128 + tid];
  }
  stats[tid] = s;
}

// ---------------------------------------------------------------- k_out
__global__ __launch_bounds__(256) void k_out(const float* __restrict__ y1,
                                             const float* __restrict__ z,
                                             const int* __restrict__ idxp,
                                             const float* __restrict__ stats,
                                             const float* __restrict__ gamma,
                                             const float* __restrict__ beta,
                                             float* __restrict__ out) {
  __shared__ float T[64][65];
  int tid = threadIdx.x;
  int lane = tid & 63;
  int w = tid >> 6;
  int b = blockIdx.x & 7;                       // XCD swizzle
  int n0 = (blockIdx.x >> 3) << 6;
  int o = lane;
  const float inv = 1.0f / (float)NTOT;
  float mean = stats[o] * inv;
  float var = fmaf(-mean, mean, stats[64 + o] * inv);
  float sc = gamma[o] * rsqrtf(var + 1e-5f);
  float bi = fmaf(-mean, sc, beta[o]);
  const float* y1b = y1 + (size_t)b * Nn * 64;
  for (int t = 0; t < 16; t++) {
    int nl = w + t * 4;
    size_t base = (size_t)b * Nn + n0 + nl;
    float zv = z[base * 64 + o];
    const int* ip = idxp + base * Kk;
    float mv = -INFINITY;
#pragma unroll
    for (int k = 0; k < Kk; k++) {
      int j = ip[k];
      float hv = y1b[(size_t)j * 64 + o] + zv;
      float hn = fmaf(hv, sc, bi);
      float a = (hn >= 0.f) ? hn : 0.2f * hn;
      mv = fmaxf(mv, a);
    }
    T[o][nl] = mv;
  }
  __syncthreads();
  for (int t = 0; t < 16; t++) {
    int oo = w * 16 + t;
    out[((size_t)b * Oo + oo) * Nn + n0 + lane] = T[oo][lane];
  }
}

// ---------------------------------------------------------------- launch
extern "C" void kernel_launch(void* const* d_in, const int* in_sizes, int n_in,
                              void* d_out, int out_size, void* d_ws, size_t ws_size,
                              hipStream_t stream) {
  const float* x = (const float*)d_in[0];
  const float* W = (const float*)d_in[1];
  const float* gamma = (const float*)d_in[2];
  const float* beta = (const float*)d_in[3];
  // d_in[4] is k (=20), baked in as Kk.

  // workspace layout (bytes):
  //   xhi  : [0,        4194304)  bf16 [b][n][c]  \ dead after k_knn;
  //   xmid : [4194304,  8388608)  bf16 [b][n][c]   } y1 overlays [0,8M),
  //   xlo  : [8388608, 12582912)  bf16 [b][n][c]  / z overlays [8M,16M)
  //   y1   : [0,        8388608)  B*N*O fp32  (k_y1z, after k_knn)
  //   z    : [8388608, 16777216)  B*N*O fp32  (k_y1z, after k_knn)
  //   sq   : [16777216,16908288)  B*N fp32
  //   stats: [16908288,16908800)  128 fp32
  //   idx20: [16908800,19530240)  B*N*K int32
  //   parts: [19530240,19792384)  512*128 fp32
  char* ws = (char*)d_ws;
  unsigned short* xhi = (unsigned short*)ws;
  unsigned short* xmid = (unsigned short*)(ws + 4194304);
  unsigned short* xlo = (unsigned short*)(ws + 8388608);
  float* y1 = (float*)ws;
  float* z = (float*)(ws + 8388608);
  float* sq = (float*)(ws + 16777216);
  float* stats = (float*)(ws + 16908288);
  int* idx = (int*)(ws + 16908800);
  float* parts = (float*)(ws + 19530240);
  float* out = (float*)d_out;

  k_split<<<Bn * (Nn / 64), 256, 0, stream>>>(x, xhi, xmid, xlo, sq);
  k_knn<<<Bn * (Nn / 32), 256, 0, stream>>>(xhi, xmid, xlo, sq, idx);
  k_y1z<<<Bn * (Nn / 64), 256, 0, stream>>>(x, W, y1, z);
  k_stats<<<Bn * (Nn / 64), 256, 0, stream>>>(y1, z, idx, parts);
  k_reduce<<<1, 128, 0, stream>>>(parts, stats);
  k_out<<<Bn * (Nn / 64), 256, 0, stream>>>(y1, z, idx, stats, gamma, beta, out);
}

// Round 10
// 530.597 us; speedup vs baseline: 1.9523x; 1.9523x over previous
//
#include <hip/hip_runtime.h>
#include <math.h>

// Problem constants (setup_inputs): B=8, C=64, N=4096, O=64, K=20
#define Bn 8
#define Cc 64
#define Nn 4096
#define Oo 64
#define Kk 20
#define QCAP 16              // per-row candidate queue capacity per tile
#define NTOT (Bn*Nn*Kk)      // 655360 elements per BN channel

typedef __attribute__((ext_vector_type(8))) short short8;
typedef __attribute__((ext_vector_type(4))) float f32x4;

__device__ __forceinline__ unsigned bf16_rn(float v) {
  unsigned u = __float_as_uint(v);
  return (u + 0x7FFFu + ((u >> 16) & 1)) >> 16;     // RN-even
}

// ---------------------------------------------------------------- k_split
// x fp32 [b][c][n] -> INTERLEAVED 3-term bf16 split xs3[b][n][{h|m|l}*64+c]
// (192 shorts/row: hi 0..63, mid 64..127, lo 128..191), plus sq[b][n].
//   h = RN(x); m = RN(x-h); l = RN(x-h-m)   (x-h, x-h-m exact in fp32)
// Interleaving makes k_knn's B-tile staging a single contiguous region.
__global__ __launch_bounds__(256) void k_split(const float* __restrict__ x,
                                               unsigned short* __restrict__ xs3,
                                               float* __restrict__ sqv) {
  __shared__ float xs[64][68];                  // [c][n], float4-friendly pad
  int tid = threadIdx.x;
  int b = blockIdx.x & 7;
  int n0 = (blockIdx.x >> 3) << 6;
  for (int i = 0; i < 4; i++) {
    int c = i * 16 + (tid >> 4);
    int n = (tid & 15) * 4;
    float4 v = *(const float4*)&x[((size_t)b * Cc + c) * Nn + n0 + n];
    *(float4*)&xs[c][n] = v;
  }
  __syncthreads();
  for (int i = 0; i < 4; i++) {
    int n = i * 16 + (tid >> 4);
    int c = (tid & 15) * 4;
    ushort4 h4, m4, l4;
    unsigned short* hp = (unsigned short*)&h4;
    unsigned short* mp = (unsigned short*)&m4;
    unsigned short* lp = (unsigned short*)&l4;
#pragma unroll
    for (int j = 0; j < 4; j++) {
      float v = xs[c + j][n];
      unsigned hb = bf16_rn(v);
      float hf = __uint_as_float(hb << 16);
      float r1 = v - hf;                                     // exact
      unsigned mb = bf16_rn(r1);
      float mf = __uint_as_float(mb << 16);
      float r2 = r1 - mf;                                    // exact
      unsigned lb = bf16_rn(r2);
      hp[j] = (unsigned short)hb;
      mp[j] = (unsigned short)mb;
      lp[j] = (unsigned short)lb;
    }
    size_t o = ((size_t)(b << 12) + n0 + n) * 192 + c;
    *(ushort4*)&xs3[o] = h4;
    *(ushort4*)&xs3[o + 64] = m4;
    *(ushort4*)&xs3[o + 128] = l4;
  }
  if (tid < 64) {
    float s = 0.f;
#pragma unroll
    for (int c = 0; c < 64; c++) { float v = xs[c][tid]; s = fmaf(v, v, s); }
    sqv[b * Nn + n0 + tid] = s;
  }
}

// ---------------------------------------------------------------- k_y1z
__global__ __launch_bounds__(256) void k_y1z(const float* __restrict__ x,
                                             const float* __restrict__ Wm,
                                             float* __restrict__ y1,
                                             float* __restrict__ z) {
  __shared__ float xs[64][68];                  // [c][n]
  __shared__ float Wl[64][129];
  int tid = threadIdx.x;
  int b = blockIdx.x & 7;
  int n0 = (blockIdx.x >> 3) << 6;
  for (int i = tid; i < 64 * 128; i += 256) Wl[i >> 7][i & 127] = Wm[i];
  for (int i = 0; i < 4; i++) {
    int c = i * 16 + (tid >> 4);
    int n = (tid & 15) * 4;
    float4 v = *(const float4*)&x[((size_t)b * Cc + c) * Nn + n0 + n];
    *(float4*)&xs[c][n] = v;
  }
  __syncthreads();
  int o = tid & 63, ng = tid >> 6;              // ng == wave id -> nb uniform
  for (int p = 0; p < 4; p++) {
    int nb = p * 16 + ng * 4;
    float a1[4] = {0.f, 0.f, 0.f, 0.f};
    float a2[4] = {0.f, 0.f, 0.f, 0.f};
#pragma unroll 8
    for (int c = 0; c < 64; c++) {
      float4 xv = *(const float4*)&xs[c][nb];   // wave-broadcast
      float w1v = Wl[o][c], w2v = Wl[o][64 + c];
      float xa[4] = {xv.x, xv.y, xv.z, xv.w};
#pragma unroll
      for (int j = 0; j < 4; j++) {
        a1[j] = fmaf(xa[j], w1v, a1[j]);
        a2[j] = fmaf(xa[j], w2v, a2[j]);
      }
    }
#pragma unroll
    for (int j = 0; j < 4; j++) {
      size_t off = ((size_t)b * Nn + n0 + nb + j) * 64 + o;
      y1[off] = a1[j];
      z[off] = a2[j] - a1[j];
    }
  }
}

// ---------------------------------------------------------------- k_knn (v10)
// Round-8 structure (8-row waves, 64-col tiles, 3-term split-bf16 MFMA Gram,
// wave-private queues, per-lane push, sorted register top-20) with:
//  - launch_bounds(256,4): round 9's (256,5) forced VGPR=48 -> hk/hix spill
//    -> 2.3GB scratch traffic. 128-reg cap fits the kernel with zero spill.
//  - interleaved xs3 staging: one contiguous B-tile region -> per tile just
//    6 loads (gp + i*2048), 6 stores to PRECOMPUTED LDS dests, gp += 12288.
//    (round 8 burned ~60 VALU/thread/tile on staging address math)
//  - QCAP 16; qk stride 20 (16B-aligned), qm stride 24 (8B-aligned rows).
__global__ __launch_bounds__(256, 4) void k_knn(const unsigned short* __restrict__ xs3,
                                                const float* __restrict__ sqv,
                                                int* __restrict__ idxout) {
  __shared__ alignas(16) short Bs[3][64][72];    // [h/m/l][m][c], padded
  __shared__ float thrS[32];
  __shared__ float sqs[64];
  __shared__ alignas(16) float qk[32][20];       // 80B rows, float4-aligned
  __shared__ alignas(16) unsigned short qm[32][24]; // 48B rows, ushort4-aligned
  __shared__ int qcnt[32];

  const int tid = threadIdx.x;
  const int lane = tid & 63;
  const int w = tid >> 6;
  const int b = blockIdx.x & 7;                  // XCD swizzle: batch per XCD
  const int n0 = (blockIdx.x >> 3) << 5;         // 128 row-blocks x 32 rows
  const int lm = lane & 15;                      // candidate col / A row slot
  const int q = lane >> 4;                       // quad: C row = q*4+r
  const int myrow = w * 8 + lane;                // valid for lane<8 (handler)
  const bool handler = (lane < 8);

  // handler state: SORTED ascending 20-list in registers (lanes 0-7)
  float hk[Kk];
  int hix[Kk];
  float hthr = INFINITY;
#pragma unroll
  for (int kk = 0; kk < Kk; kk++) { hk[kk] = INFINITY; hix[kk] = 0; }

  if (handler) { thrS[myrow] = INFINITY; qcnt[myrow] = 0; }  // wave-private init

  // A fragments from interleaved rows: wave w owns rows n0+w*8..+7 (8-15 dup)
  const size_t arow = ((size_t)(b << 12) + n0 + w * 8 + (lm & 7)) * 192;
  short8 ah0 = *(const short8*)&xs3[arow + q * 8];
  short8 ah1 = *(const short8*)&xs3[arow + 32 + q * 8];
  short8 am0 = *(const short8*)&xs3[arow + 64 + q * 8];
  short8 am1 = *(const short8*)&xs3[arow + 96 + q * 8];
  short8 al0 = *(const short8*)&xs3[arow + 128 + q * 8];
  short8 al1 = *(const short8*)&xs3[arow + 160 + q * 8];

  // staging: per-thread source pointer (incremented) + 6 fixed LDS dests
  const unsigned short* gp = xs3 + (size_t)(b << 12) * 192 + tid * 8;
  short* ld[6];
#pragma unroll
  for (int i = 0; i < 6; i++) {
    int f = i * 256 + tid;                       // chunk id in [0,1536)
    int r = f / 24;                              // B row
    int rem = f - r * 24;
    int layer = rem >> 3;
    int qq = rem & 7;
    ld[i] = &Bs[layer][r][qq * 8];
  }

  f32x4 acc[4];

  for (int m0 = 0; m0 < Nn; m0 += 64) {
    __syncthreads();                              // all waves done reading Bs
#pragma unroll
    for (int i = 0; i < 6; i++) {
      short8 v = *(const short8*)(gp + i * 2048);
      *(short8*)ld[i] = v;
    }
    gp += 12288;                                  // next 64 rows
    if (tid < 16) ((float4*)sqs)[tid] = ((const float4*)(sqv + b * Nn + m0))[tid];
    __syncthreads();                              // staging visible

#pragma unroll
    for (int g = 0; g < 4; g++) {
      const int mr = g * 16 + lm;
      short8 bh0 = *(const short8*)&Bs[0][mr][q * 8];
      short8 bh1 = *(const short8*)&Bs[0][mr][32 + q * 8];
      short8 bm0 = *(const short8*)&Bs[1][mr][q * 8];
      short8 bm1 = *(const short8*)&Bs[1][mr][32 + q * 8];
      short8 bl0 = *(const short8*)&Bs[2][mr][q * 8];
      short8 bl1 = *(const short8*)&Bs[2][mr][32 + q * 8];
      f32x4 a = (f32x4){0.f, 0.f, 0.f, 0.f};
      a = __builtin_amdgcn_mfma_f32_16x16x32_bf16(am0, bm0, a, 0, 0, 0);  // mm
      a = __builtin_amdgcn_mfma_f32_16x16x32_bf16(am1, bm1, a, 0, 0, 0);
      a = __builtin_amdgcn_mfma_f32_16x16x32_bf16(ah0, bl0, a, 0, 0, 0);  // hl
      a = __builtin_amdgcn_mfma_f32_16x16x32_bf16(ah1, bl1, a, 0, 0, 0);
      a = __builtin_amdgcn_mfma_f32_16x16x32_bf16(al0, bh0, a, 0, 0, 0);  // lh
      a = __builtin_amdgcn_mfma_f32_16x16x32_bf16(al1, bh1, a, 0, 0, 0);
      a = __builtin_amdgcn_mfma_f32_16x16x32_bf16(ah0, bm0, a, 0, 0, 0);  // hm
      a = __builtin_amdgcn_mfma_f32_16x16x32_bf16(ah1, bm1, a, 0, 0, 0);
      a = __builtin_amdgcn_mfma_f32_16x16x32_bf16(am0, bh0, a, 0, 0, 0);  // mh
      a = __builtin_amdgcn_mfma_f32_16x16x32_bf16(am1, bh1, a, 0, 0, 0);
      a = __builtin_amdgcn_mfma_f32_16x16x32_bf16(ah0, bh0, a, 0, 0, 0);  // hh
      a = __builtin_amdgcn_mfma_f32_16x16x32_bf16(ah1, bh1, a, 0, 0, 0);
      acc[g] = a;
    }

    // keys = sq[m] - 2*dot; only q<2 lanes hold unique query rows (0..7)
    unsigned pend = 0;
    if (q < 2) {
      float tl[4];
#pragma unroll
      for (int r = 0; r < 4; r++) tl[r] = thrS[w * 8 + q * 4 + r];
#pragma unroll
      for (int g = 0; g < 4; g++) {
        float sv = sqs[g * 16 + lm];
#pragma unroll
        for (int r = 0; r < 4; r++) {
          float key = fmaf(-2.f, acc[g][r], sv);
          acc[g][r] = key;
          if (key < tl[r]) pend |= 1u << (g * 4 + r);
        }
      }
    }

    // wave-private push / drain: NO __syncthreads (DS in-order per wave)
    for (;;) {
      if (pend) {
#pragma unroll
        for (int g = 0; g < 4; g++) {
#pragma unroll
          for (int r = 0; r < 4; r++) {
            unsigned bit = 1u << (g * 4 + r);
            if (pend & bit) {
              int row = w * 8 + q * 4 + r;
              int p = atomicAdd(&qcnt[row], 1);
              if (p < QCAP) {
                qk[row][p] = acc[g][r];
                qm[row][p] = (unsigned short)(m0 + g * 16 + lm);
                pend &= ~bit;
              }
              // else: bit stays set -> retry after drain
            }
          }
        }
      }
      unsigned long long anyovf = __ballot(pend != 0);

      if (handler) {                             // 8 lanes drain 8 rows
        int cn = qcnt[myrow];
        if (cn > QCAP) cn = QCAP;
        for (int p0 = 0; p0 < cn; p0 += 4) {
          float4 kv4 = *(const float4*)&qk[myrow][p0];
          ushort4 mv4 = *(const ushort4*)&qm[myrow][p0];
          float kva[4] = {kv4.x, kv4.y, kv4.z, kv4.w};
          unsigned short mva[4] = {mv4.x, mv4.y, mv4.z, mv4.w};
#pragma unroll
          for (int j = 0; j < 4; j++) {
            if (p0 + j < cn && kva[j] < hthr) {
              float kv = kva[j];
              int mvi = (int)mva[j];
              bool cm[Kk];
#pragma unroll
              for (int kk = 0; kk < Kk; kk++) cm[kk] = kv < hk[kk];
#pragma unroll
              for (int kk = Kk - 1; kk >= 1; kk--) {
                hk[kk]  = cm[kk] ? (cm[kk - 1] ? hk[kk - 1]  : kv ) : hk[kk];
                hix[kk] = cm[kk] ? (cm[kk - 1] ? hix[kk - 1] : mvi) : hix[kk];
              }
              if (cm[0]) { hk[0] = kv; hix[0] = mvi; }
              hthr = hk[Kk - 1];
            }
          }
        }
        if (cn) { qcnt[myrow] = 0; thrS[myrow] = hthr; }
      }
      if (!anyovf) break;
      // refilter surviving bits against the tightened thresholds
      if (pend) {
        float tl[4];
#pragma unroll
        for (int r = 0; r < 4; r++) tl[r] = thrS[w * 8 + q * 4 + r];
#pragma unroll
        for (int g = 0; g < 4; g++)
#pragma unroll
          for (int r = 0; r < 4; r++) {
            unsigned bit = 1u << (g * 4 + r);
            if ((pend & bit) && acc[g][r] >= tl[r]) pend &= ~bit;
          }
      }
    }
  }

  // final write: handler lane owns row myrow's sorted list
  if (handler) {
    size_t base = ((size_t)b * Nn + n0 + myrow) * Kk;
#pragma unroll
    for (int kk = 0; kk < Kk; kk++) idxout[base + kk] = hix[kk];
  }
}

// ---------------------------------------------------------------- k_stats
__global__ __launch_bounds__(256) void k_stats(const float* __restrict__ y1,
                                               const float* __restrict__ z,
                                               const int* __restrict__ idxp,
                                               float* __restrict__ parts) {
  __shared__ float rs[4][64];
  __shared__ float rq[4][64];
  int tid = threadIdx.x;
  int o = tid & 63, g = tid >> 6;
  int b = blockIdx.x & 7;                       // XCD swizzle
  int n0 = (blockIdx.x >> 3) << 6;
  const float* y1b = y1 + (size_t)b * Nn * 64;
  float s = 0.f, ss = 0.f;
  for (int t = 0; t < 16; t++) {
    int n = n0 + g + t * 4;
    size_t base = (size_t)b * Nn + n;
    float zv = z[base * 64 + o];
    const int* ip = idxp + base * Kk;
#pragma unroll
    for (int k = 0; k < Kk; k++) {
      int j = ip[k];
      float hv = y1b[(size_t)j * 64 + o] + zv;
      s += hv;
      ss = fmaf(hv, hv, ss);
    }
  }
  rs[g][o] = s;
  rq[g][o] = ss;
  __syncthreads();
  if (tid < 64) {
    parts[(size_t)blockIdx.x * 128 + tid] = rs[0][tid] + rs[1][tid] + rs[2][tid] + rs[3][tid];
    parts[(size_t)blockIdx.x * 128 + 64 + tid] = rq[0][tid] + rq[1][tid] + rq[2][tid] + rq[3][tid];
  }
}

// ---------------------------------------------------------------- k_reduce
__global__ __launch_bounds__(128) void k_reduce(const float* __restrict__ parts,
                                                float* __restrict__ stats) {
  int tid = threadIdx.x;                         // [0,128)
  float s = 0.f;
  for (int i = 0; i < 512; i += 4) {
    s += parts[(size_t)i * 128 + tid] + parts[(size_t)(i + 1) * 128 + tid] +
         parts[(size_t)(i + 2) * 128 + tid] + parts[(size_t)(i + 3) * 128 + tid];
  }
  stats[tid] = s;
}

// ---------------------------------------------------------------- k_out
__global__ __launch_bounds__(256) void k_out(const float* __restrict__ y1,
                                             const float* __restrict__ z,
                                             const int* __restrict__ idxp,
                                             const float* __restrict__ stats,
                                             const float* __restrict__ gamma,
                                             const float* __restrict__ beta,
                                             float* __restrict__ out) {
  __shared__ float T[64][65];
  int tid = threadIdx.x;
  int lane = tid & 63;
  int w = tid >> 6;
  int b = blockIdx.x & 7;                       // XCD swizzle
  int n0 = (blockIdx.x >> 3) << 6;
  int o = lane;
  const float inv = 1.0f / (float)NTOT;
  float mean = stats[o] * inv;
  float var = fmaf(-mean, mean, stats[64 + o] * inv);
  float sc = gamma[o] * rsqrtf(var + 1e-5f);
  float bi = fmaf(-mean, sc, beta[o]);
  const float* y1b = y1 + (size_t)b * Nn * 64;
  for (int t = 0; t < 16; t++) {
    int nl = w + t * 4;
    size_t base = (size_t)b * Nn + n0 + nl;
    float zv = z[base * 64 + o];
    const int* ip = idxp + base * Kk;
    float mv = -INFINITY;
#pragma unroll
    for (int k = 0; k < Kk; k++) {
      int j = ip[k];
      float hv = y1b[(size_t)j * 64 + o] + zv;
      float hn = fmaf(hv, sc, bi);
      float a = (hn >= 0.f) ? hn : 0.2f * hn;
      mv = fmaxf(mv, a);
    }
    T[o][nl] = mv;
  }
  __syncthreads();
  for (int t = 0; t < 16; t++) {
    int oo = w * 16 + t;
    out[((size_t)b * Oo + oo) * Nn + n0 + lane] = T[oo][lane];
  }
}

// ---------------------------------------------------------------- launch
extern "C" void kernel_launch(void* const* d_in, const int* in_sizes, int n_in,
                              void* d_out, int out_size, void* d_ws, size_t ws_size,
                              hipStream_t stream) {
  const float* x = (const float*)d_in[0];
  const float* W = (const float*)d_in[1];
  const float* gamma = (const float*)d_in[2];
  const float* beta = (const float*)d_in[3];
  // d_in[4] is k (=20), baked in as Kk.

  // workspace layout (bytes):
  //   xs3  : [0,       12582912)  bf16 interleaved [b][n][3*64]  (dead after
  //                                k_knn; y1 overlays [0,8M), z [8M,16M))
  //   y1   : [0,        8388608)  B*N*O fp32  (k_y1z, after k_knn)
  //   z    : [8388608, 16777216)  B*N*O fp32  (k_y1z, after k_knn)
  //   sq   : [16777216,16908288)  B*N fp32
  //   stats: [16908288,16908800)  128 fp32
  //   idx20: [16908800,19530240)  B*N*K int32
  //   parts: [19530240,19792384)  512*128 fp32
  char* ws = (char*)d_ws;
  unsigned short* xs3 = (unsigned short*)ws;
  float* y1 = (float*)ws;
  float* z = (float*)(ws + 8388608);
  float* sq = (float*)(ws + 16777216);
  float* stats = (float*)(ws + 16908288);
  int* idx = (int*)(ws + 16908800);
  float* parts = (float*)(ws + 19530240);
  float* out = (float*)d_out;

  k_split<<<Bn * (Nn / 64), 256, 0, stream>>>(x, xs3, sq);
  k_knn<<<Bn * (Nn / 32), 256, 0, stream>>>(xs3, sq, idx);
  k_y1z<<<Bn * (Nn / 64), 256, 0, stream>>>(x, W, y1, z);
  k_stats<<<Bn * (Nn / 64), 256, 0, stream>>>(y1, z, idx, parts);
  k_reduce<<<1, 128, 0, stream>>>(parts, stats);
  k_out<<<Bn * (Nn / 64), 256, 0, stream>>>(y1, z, idx, stats, gamma, beta, out);
}

// Round 11
// 466.842 us; speedup vs baseline: 2.2189x; 1.1366x over previous
//
#include <hip/hip_runtime.h>
#include <math.h>

// Problem constants (setup_inputs): B=8, C=64, N=4096, O=64, K=20
#define Bn 8
#define Cc 64
#define Nn 4096
#define Oo 64
#define Kk 20
#define Kh 10                // half-list size (rank-split pair handlers)
#define QCAP 16              // per-row candidate queue capacity per tile
#define NTOT (Bn*Nn*Kk)      // 655360 elements per BN channel

typedef __attribute__((ext_vector_type(8))) short short8;
typedef __attribute__((ext_vector_type(4))) float f32x4;

__device__ __forceinline__ unsigned bf16_rn(float v) {
  unsigned u = __float_as_uint(v);
  return (u + 0x7FFFu + ((u >> 16) & 1)) >> 16;     // RN-even
}

// ---------------------------------------------------------------- k_split
// x fp32 [b][c][n] -> INTERLEAVED 3-term bf16 split xs3[b][n][{h|m|l}*64+c]
// (192 shorts/row), plus sq[b][n].
//   h = RN(x); m = RN(x-h); l = RN(x-h-m)   (x-h, x-h-m exact in fp32)
__global__ __launch_bounds__(256) void k_split(const float* __restrict__ x,
                                               unsigned short* __restrict__ xs3,
                                               float* __restrict__ sqv) {
  __shared__ float xs[64][68];                  // [c][n], float4-friendly pad
  int tid = threadIdx.x;
  int b = blockIdx.x & 7;
  int n0 = (blockIdx.x >> 3) << 6;
  for (int i = 0; i < 4; i++) {
    int c = i * 16 + (tid >> 4);
    int n = (tid & 15) * 4;
    float4 v = *(const float4*)&x[((size_t)b * Cc + c) * Nn + n0 + n];
    *(float4*)&xs[c][n] = v;
  }
  __syncthreads();
  for (int i = 0; i < 4; i++) {
    int n = i * 16 + (tid >> 4);
    int c = (tid & 15) * 4;
    ushort4 h4, m4, l4;
    unsigned short* hp = (unsigned short*)&h4;
    unsigned short* mp = (unsigned short*)&m4;
    unsigned short* lp = (unsigned short*)&l4;
#pragma unroll
    for (int j = 0; j < 4; j++) {
      float v = xs[c + j][n];
      unsigned hb = bf16_rn(v);
      float hf = __uint_as_float(hb << 16);
      float r1 = v - hf;                                     // exact
      unsigned mb = bf16_rn(r1);
      float mf = __uint_as_float(mb << 16);
      float r2 = r1 - mf;                                    // exact
      unsigned lb = bf16_rn(r2);
      hp[j] = (unsigned short)hb;
      mp[j] = (unsigned short)mb;
      lp[j] = (unsigned short)lb;
    }
    size_t o = ((size_t)(b << 12) + n0 + n) * 192 + c;
    *(ushort4*)&xs3[o] = h4;
    *(ushort4*)&xs3[o + 64] = m4;
    *(ushort4*)&xs3[o + 128] = l4;
  }
  if (tid < 64) {
    float s = 0.f;
#pragma unroll
    for (int c = 0; c < 64; c++) { float v = xs[c][tid]; s = fmaf(v, v, s); }
    sqv[b * Nn + n0 + tid] = s;
  }
}

// ---------------------------------------------------------------- k_y1z
__global__ __launch_bounds__(256) void k_y1z(const float* __restrict__ x,
                                             const float* __restrict__ Wm,
                                             float* __restrict__ y1,
                                             float* __restrict__ z) {
  __shared__ float xs[64][68];                  // [c][n]
  __shared__ float Wl[64][129];
  int tid = threadIdx.x;
  int b = blockIdx.x & 7;
  int n0 = (blockIdx.x >> 3) << 6;
  for (int i = tid; i < 64 * 128; i += 256) Wl[i >> 7][i & 127] = Wm[i];
  for (int i = 0; i < 4; i++) {
    int c = i * 16 + (tid >> 4);
    int n = (tid & 15) * 4;
    float4 v = *(const float4*)&x[((size_t)b * Cc + c) * Nn + n0 + n];
    *(float4*)&xs[c][n] = v;
  }
  __syncthreads();
  int o = tid & 63, ng = tid >> 6;              // ng == wave id -> nb uniform
  for (int p = 0; p < 4; p++) {
    int nb = p * 16 + ng * 4;
    float a1[4] = {0.f, 0.f, 0.f, 0.f};
    float a2[4] = {0.f, 0.f, 0.f, 0.f};
#pragma unroll 8
    for (int c = 0; c < 64; c++) {
      float4 xv = *(const float4*)&xs[c][nb];   // wave-broadcast
      float w1v = Wl[o][c], w2v = Wl[o][64 + c];
      float xa[4] = {xv.x, xv.y, xv.z, xv.w};
#pragma unroll
      for (int j = 0; j < 4; j++) {
        a1[j] = fmaf(xa[j], w1v, a1[j]);
        a2[j] = fmaf(xa[j], w2v, a2[j]);
      }
    }
#pragma unroll
    for (int j = 0; j < 4; j++) {
      size_t off = ((size_t)b * Nn + n0 + nb + j) * 64 + o;
      y1[off] = a1[j];
      z[off] = a2[j] - a1[j];
    }
  }
}

// ---------------------------------------------------------------- k_knn (v11)
// Round-10 structure (8-row waves, 64-col tiles, 3-term split-bf16 MFMA Gram,
// wave-private queues, per-lane push) with RANK-SPLIT PAIR HANDLERS:
// row r's sorted top-20 lives across a lane pair — even lane (L) holds ranks
// 0-9, odd lane (H) holds ranks 10-19. Per drained candidate: L computes the
// value flowing to H (pass = kv<Lmax ? evicted Lmax : kv) in ~8 instr + one
// shfl_xor(1); then BOTH lanes run the same 10-deep insert body concurrently
// (~50 instr vs round 10's ~96 for the 20-deep chain). Union = old20-max+kv
// (exact replace-max). 16 handler lanes/wave; threshold = H's hk[9].
__global__ __launch_bounds__(256, 4) void k_knn(const unsigned short* __restrict__ xs3,
                                                const float* __restrict__ sqv,
                                                int* __restrict__ idxout) {
  __shared__ alignas(16) short Bs[3][64][72];    // [h/m/l][m][c], padded
  __shared__ float thrS[32];
  __shared__ float sqs[64];
  __shared__ alignas(16) float qk[32][20];       // 80B rows, float4-aligned
  __shared__ alignas(16) unsigned short qm[32][24]; // 48B rows, ushort4-aligned
  __shared__ int qcnt[32];

  const int tid = threadIdx.x;
  const int lane = tid & 63;
  const int w = tid >> 6;
  const int b = blockIdx.x & 7;                  // XCD swizzle: batch per XCD
  const int n0 = (blockIdx.x >> 3) << 5;         // 128 row-blocks x 32 rows
  const int lm = lane & 15;                      // candidate col / A row slot
  const int q = lane >> 4;                       // quad: C row = q*4+r
  const bool handler = (lane < 16);
  const int hrow = w * 8 + (lane >> 1);          // row for this handler pair
  const bool isL = (lane & 1) == 0;              // L = ranks 0-9, H = 10-19

  // handler half-list: sorted ascending 10-list in registers
  float hk[Kh];
  int hix[Kh];
#pragma unroll
  for (int kk = 0; kk < Kh; kk++) { hk[kk] = INFINITY; hix[kk] = 0; }

  if (handler && !isL) { thrS[hrow] = INFINITY; qcnt[hrow] = 0; }

  // A fragments from interleaved rows: wave w owns rows n0+w*8..+7 (8-15 dup)
  const size_t arow = ((size_t)(b << 12) + n0 + w * 8 + (lm & 7)) * 192;
  short8 ah0 = *(const short8*)&xs3[arow + q * 8];
  short8 ah1 = *(const short8*)&xs3[arow + 32 + q * 8];
  short8 am0 = *(const short8*)&xs3[arow + 64 + q * 8];
  short8 am1 = *(const short8*)&xs3[arow + 96 + q * 8];
  short8 al0 = *(const short8*)&xs3[arow + 128 + q * 8];
  short8 al1 = *(const short8*)&xs3[arow + 160 + q * 8];

  // staging: per-thread source pointer (incremented) + 6 fixed LDS dests
  const unsigned short* gp = xs3 + (size_t)(b << 12) * 192 + tid * 8;
  short* ld[6];
#pragma unroll
  for (int i = 0; i < 6; i++) {
    int f = i * 256 + tid;                       // chunk id in [0,1536)
    int r = f / 24;                              // B row
    int rem = f - r * 24;
    int layer = rem >> 3;
    int qq = rem & 7;
    ld[i] = &Bs[layer][r][qq * 8];
  }

  f32x4 acc[4];

  for (int m0 = 0; m0 < Nn; m0 += 64) {
    __syncthreads();                              // all waves done reading Bs
#pragma unroll
    for (int i = 0; i < 6; i++) {
      short8 v = *(const short8*)(gp + i * 2048);
      *(short8*)ld[i] = v;
    }
    gp += 12288;                                  // next 64 rows
    if (tid < 16) ((float4*)sqs)[tid] = ((const float4*)(sqv + b * Nn + m0))[tid];
    __syncthreads();                              // staging visible

#pragma unroll
    for (int g = 0; g < 4; g++) {
      const int mr = g * 16 + lm;
      short8 bh0 = *(const short8*)&Bs[0][mr][q * 8];
      short8 bh1 = *(const short8*)&Bs[0][mr][32 + q * 8];
      short8 bm0 = *(const short8*)&Bs[1][mr][q * 8];
      short8 bm1 = *(const short8*)&Bs[1][mr][32 + q * 8];
      short8 bl0 = *(const short8*)&Bs[2][mr][q * 8];
      short8 bl1 = *(const short8*)&Bs[2][mr][32 + q * 8];
      f32x4 a = (f32x4){0.f, 0.f, 0.f, 0.f};
      a = __builtin_amdgcn_mfma_f32_16x16x32_bf16(am0, bm0, a, 0, 0, 0);  // mm
      a = __builtin_amdgcn_mfma_f32_16x16x32_bf16(am1, bm1, a, 0, 0, 0);
      a = __builtin_amdgcn_mfma_f32_16x16x32_bf16(ah0, bl0, a, 0, 0, 0);  // hl
      a = __builtin_amdgcn_mfma_f32_16x16x32_bf16(ah1, bl1, a, 0, 0, 0);
      a = __builtin_amdgcn_mfma_f32_16x16x32_bf16(al0, bh0, a, 0, 0, 0);  // lh
      a = __builtin_amdgcn_mfma_f32_16x16x32_bf16(al1, bh1, a, 0, 0, 0);
      a = __builtin_amdgcn_mfma_f32_16x16x32_bf16(ah0, bm0, a, 0, 0, 0);  // hm
      a = __builtin_amdgcn_mfma_f32_16x16x32_bf16(ah1, bm1, a, 0, 0, 0);
      a = __builtin_amdgcn_mfma_f32_16x16x32_bf16(am0, bh0, a, 0, 0, 0);  // mh
      a = __builtin_amdgcn_mfma_f32_16x16x32_bf16(am1, bh1, a, 0, 0, 0);
      a = __builtin_amdgcn_mfma_f32_16x16x32_bf16(ah0, bh0, a, 0, 0, 0);  // hh
      a = __builtin_amdgcn_mfma_f32_16x16x32_bf16(ah1, bh1, a, 0, 0, 0);
      acc[g] = a;
    }

    // keys = sq[m] - 2*dot; only q<2 lanes hold unique query rows (0..7)
    unsigned pend = 0;
    if (q < 2) {
      float tl[4];
#pragma unroll
      for (int r = 0; r < 4; r++) tl[r] = thrS[w * 8 + q * 4 + r];
#pragma unroll
      for (int g = 0; g < 4; g++) {
        float sv = sqs[g * 16 + lm];
#pragma unroll
        for (int r = 0; r < 4; r++) {
          float key = fmaf(-2.f, acc[g][r], sv);
          acc[g][r] = key;
          if (key < tl[r]) pend |= 1u << (g * 4 + r);
        }
      }
    }

    // wave-private push / drain: NO __syncthreads (DS in-order per wave)
    for (;;) {
      if (pend) {
#pragma unroll
        for (int g = 0; g < 4; g++) {
#pragma unroll
          for (int r = 0; r < 4; r++) {
            unsigned bit = 1u << (g * 4 + r);
            if (pend & bit) {
              int row = w * 8 + q * 4 + r;
              int p = atomicAdd(&qcnt[row], 1);
              if (p < QCAP) {
                qk[row][p] = acc[g][r];
                qm[row][p] = (unsigned short)(m0 + g * 16 + lm);
                pend &= ~bit;
              }
              // else: bit stays set -> retry after drain
            }
          }
        }
      }
      unsigned long long anyovf = __ballot(pend != 0);

      if (handler) {                             // 16 lanes: 8 rows x (L,H)
        int cn = qcnt[hrow];                     // same for both pair lanes
        if (cn > QCAP) cn = QCAP;
        for (int p0 = 0; p0 < cn; p0 += 4) {
          float4 kv4 = *(const float4*)&qk[hrow][p0];      // pair-broadcast
          ushort4 mv4 = *(const ushort4*)&qm[hrow][p0];
          float kva[4] = {kv4.x, kv4.y, kv4.z, kv4.w};
          unsigned short mva[4] = {mv4.x, mv4.y, mv4.z, mv4.w};
#pragma unroll
          for (int j = 0; j < 4; j++) {
            bool valid = (p0 + j < cn);
            float kv = kva[j];
            int ki = (int)mva[j];
            // L decides what flows to H: its evicted max, or kv itself
            bool lins = kv < hk[Kh - 1];
            float pv = lins ? hk[Kh - 1] : kv;
            int pi = lins ? hix[Kh - 1] : ki;
            float rv = __shfl_xor(pv, 1);
            int ri = __shfl_xor(pi, 1);
            float mval = isL ? kv : rv;
            int midx = isL ? ki : ri;
            if (valid && mval < hk[Kh - 1]) {    // both roles: same 10-insert
              bool cm[Kh];
#pragma unroll
              for (int kk = 0; kk < Kh; kk++) cm[kk] = mval < hk[kk];
#pragma unroll
              for (int kk = Kh - 1; kk >= 1; kk--) {
                hk[kk]  = cm[kk] ? (cm[kk - 1] ? hk[kk - 1]  : mval) : hk[kk];
                hix[kk] = cm[kk] ? (cm[kk - 1] ? hix[kk - 1] : midx) : hix[kk];
              }
              if (cm[0]) { hk[0] = mval; hix[0] = midx; }
            }
          }
        }
        if (cn && !isL) { qcnt[hrow] = 0; thrS[hrow] = hk[Kh - 1]; }
      }
      if (!anyovf) break;
      // refilter surviving bits against the tightened thresholds
      if (pend) {
        float tl[4];
#pragma unroll
        for (int r = 0; r < 4; r++) tl[r] = thrS[w * 8 + q * 4 + r];
#pragma unroll
        for (int g = 0; g < 4; g++)
#pragma unroll
          for (int r = 0; r < 4; r++) {
            unsigned bit = 1u << (g * 4 + r);
            if ((pend & bit) && acc[g][r] >= tl[r]) pend &= ~bit;
          }
      }
    }
  }

  // final write: L lane writes ranks 0-9, H lane ranks 10-19
  if (handler) {
    size_t base = ((size_t)b * Nn + n0 + hrow) * Kk + (isL ? 0 : Kh);
#pragma unroll
    for (int kk = 0; kk < Kh; kk++) idxout[base + kk] = hix[kk];
  }
}

// ---------------------------------------------------------------- k_stats
__global__ __launch_bounds__(256) void k_stats(const float* __restrict__ y1,
                                               const float* __restrict__ z,
                                               const int* __restrict__ idxp,
                                               float* __restrict__ parts) {
  __shared__ float rs[4][64];
  __shared__ float rq[4][64];
  int tid = threadIdx.x;
  int o = tid & 63, g = tid >> 6;
  int b = blockIdx.x & 7;                       // XCD swizzle
  int n0 = (blockIdx.x >> 3) << 6;
  const float* y1b = y1 + (size_t)b * Nn * 64;
  float s = 0.f, ss = 0.f;
  for (int t = 0; t < 16; t++) {
    int n = n0 + g + t * 4;
    size_t base = (size_t)b * Nn + n;
    float zv = z[base * 64 + o];
    const int* ip = idxp + base * Kk;
#pragma unroll
    for (int k = 0; k < Kk; k++) {
      int j = ip[k];
      float hv = y1b[(size_t)j * 64 + o] + zv;
      s += hv;
      ss = fmaf(hv, hv, ss);
    }
  }
  rs[g][o] = s;
  rq[g][o] = ss;
  __syncthreads();
  if (tid < 64) {
    parts[(size_t)blockIdx.x * 128 + tid] = rs[0][tid] + rs[1][tid] + rs[2][tid] + rs[3][tid];
    parts[(size_t)blockIdx.x * 128 + 64 + tid] = rq[0][tid] + rq[1][tid] + rq[2][tid] + rq[3][tid];
  }
}

// ---------------------------------------------------------------- k_reduce
__global__ __launch_bounds__(128) void k_reduce(const float* __restrict__ parts,
                                                float* __restrict__ stats) {
  int tid = threadIdx.x;                         // [0,128)
  float s = 0.f;
  for (int i = 0; i < 512; i += 4) {
    s += parts[(size_t)i * 128 + tid] + parts[(size_t)(i + 1) * 128 + tid] +
         parts[(size_t)(i + 2) * 128 + tid] + parts[(size_t)(i + 3) * 128 + tid];
  }
  stats[tid] = s;
}

// ---------------------------------------------------------------- k_out
__global__ __launch_bounds__(256) void k_out(const float* __restrict__ y1,
                                             const float* __restrict__ z,
                                             const int* __restrict__ idxp,
                                             const float* __restrict__ stats,
                                             const float* __restrict__ gamma,
                                             const float* __restrict__ beta,
                                             float* __restrict__ out) {
  __shared__ float T[64][65];
  int tid = threadIdx.x;
  int lane = tid & 63;
  int w = tid >> 6;
  int b = blockIdx.x & 7;                       // XCD swizzle
  int n0 = (blockIdx.x >> 3) << 6;
  int o = lane;
  const float inv = 1.0f / (float)NTOT;
  float mean = stats[o] * inv;
  float var = fmaf(-mean, mean, stats[64 + o] * inv);
  float sc = gamma[o] * rsqrtf(var + 1e-5f);
  float bi = fmaf(-mean, sc, beta[o]);
  const float* y1b = y1 + (size_t)b * Nn * 64;
  for (int t = 0; t < 16; t++) {
    int nl = w + t * 4;
    size_t base = (size_t)b * Nn + n0 + nl;
    float zv = z[base * 64 + o];
    const int* ip = idxp + base * Kk;
    float mv = -INFINITY;
#pragma unroll
    for (int k = 0; k < Kk; k++) {
      int j = ip[k];
      float hv = y1b[(size_t)j * 64 + o] + zv;
      float hn = fmaf(hv, sc, bi);
      float a = (hn >= 0.f) ? hn : 0.2f * hn;
      mv = fmaxf(mv, a);
    }
    T[o][nl] = mv;
  }
  __syncthreads();
  for (int t = 0; t < 16; t++) {
    int oo = w * 16 + t;
    out[((size_t)b * Oo + oo) * Nn + n0 + lane] = T[oo][lane];
  }
}

// ---------------------------------------------------------------- launch
extern "C" void kernel_launch(void* const* d_in, const int* in_sizes, int n_in,
                              void* d_out, int out_size, void* d_ws, size_t ws_size,
                              hipStream_t stream) {
  const float* x = (const float*)d_in[0];
  const float* W = (const float*)d_in[1];
  const float* gamma = (const float*)d_in[2];
  const float* beta = (const float*)d_in[3];
  // d_in[4] is k (=20), baked in as Kk.

  // workspace layout (bytes):
  //   xs3  : [0,       12582912)  bf16 interleaved [b][n][3*64]  (dead after
  //                                k_knn; y1 overlays [0,8M), z [8M,16M))
  //   y1   : [0,        8388608)  B*N*O fp32  (k_y1z, after k_knn)
  //   z    : [8388608, 16777216)  B*N*O fp32  (k_y1z, after k_knn)
  //   sq   : [16777216,16908288)  B*N fp32
  //   stats: [16908288,16908800)  128 fp32
  //   idx20: [16908800,19530240)  B*N*K int32
  //   parts: [19530240,19792384)  512*128 fp32
  char* ws = (char*)d_ws;
  unsigned short* xs3 = (unsigned short*)ws;
  float* y1 = (float*)ws;
  float* z = (float*)(ws + 8388608);
  float* sq = (float*)(ws + 16777216);
  float* stats = (float*)(ws + 16908288);
  int* idx = (int*)(ws + 16908800);
  float* parts = (float*)(ws + 19530240);
  float* out = (float*)d_out;

  k_split<<<Bn * (Nn / 64), 256, 0, stream>>>(x, xs3, sq);
  k_knn<<<Bn * (Nn / 32), 256, 0, stream>>>(xs3, sq, idx);
  k_y1z<<<Bn * (Nn / 64), 256, 0, stream>>>(x, W, y1, z);
  k_stats<<<Bn * (Nn / 64), 256, 0, stream>>>(y1, z, idx, parts);
  k_reduce<<<1, 128, 0, stream>>>(parts, stats);
  k_out<<<Bn * (Nn / 64), 256, 0, stream>>>(y1, z, idx, stats, gamma, beta, out);
}